// Round 4
// baseline (688.536 us; speedup 1.0000x reference)
//
#include <hip/hip_runtime.h>
#include <stdint.h>

#define Bsz   256
#define Tlen  1024
#define Vocab 128
#define Hdim  128
#define NTHR  256
#define WTN   ((Vocab - 1) * Hdim)   // 127*128 = 16256 floats

// h LDS layout: 8 chunks of 16 floats, chunk stride 20 floats -> chunk bases
// hit banks {0,20,8,28,16,4,24,12}: all 8 distinct bank-quads, so the 8-way
// chunked ds_read_b128 pattern is conflict-free. HADDR maps element->slot.
#define HSTR  20
#define HBUFN (8 * HSTR)             // 160 floats per buffer
#define HADDR(e) ((((e) >> 4) * HSTR) + ((e) & 15))

__device__ __forceinline__ float tanh_fast(float x) {
    // tanh(x) = 1 - 2/(exp2(2x*log2e)+1); exact limits at +-inf
    float e = __builtin_amdgcn_exp2f(x * 2.885390081777927f);
    return 1.0f - 2.0f * __builtin_amdgcn_rcpf(e + 1.0f);
}

// quad-level butterfly adds via DPP (VALU-speed, no LDS pipe)
__device__ __forceinline__ float dpp_xor1(float s) {
    return __int_as_float(__builtin_amdgcn_mov_dpp(__float_as_int(s), 0xB1, 0xF, 0xF, true)); // quad_perm(1,0,3,2)
}
__device__ __forceinline__ float dpp_xor2(float s) {
    return __int_as_float(__builtin_amdgcn_mov_dpp(__float_as_int(s), 0x4E, 0xF, 0xF, true)); // quad_perm(2,3,0,1)
}

// Tiny prep: transpose W_ih (H x V-1) -> wt (V-1 x H).
__global__ __launch_bounds__(256) void transpose_kernel(
    const float* __restrict__ W_ih, float* __restrict__ wt)
{
    int idx = blockIdx.x * 256 + threadIdx.x;
    if (idx < WTN) {
        int h = idx / (Vocab - 1);
        int f = idx - h * (Vocab - 1);
        wt[f * Hdim + h] = W_ih[idx];   // wt[f][h] = W_ih[h][f]
    }
}

// One block (256 thr, 4 waves) per sequence. 8-lane group G = w*8 + (l>>3)
// owns outputs {4G..4G+3} (C=4); lane j = l&7 covers k in [16j,16j+16)
// (S=8). 64 W_hh floats pinned in VGPRs per lane. LDS read traffic per
// step: 256 lanes * 64 B = 16 KB (vs 64 KB in R3). Reduction: xor1/xor2
// DPP + one shfl_xor(4). One barrier per step, zero global ops in loop.
__global__ __launch_bounds__(NTHR, 1) void rnn_kernel(
    const float* __restrict__ x, const float* __restrict__ wt,
    const float* __restrict__ W_hh,
    const float* __restrict__ b_ih, const float* __restrict__ b_hh,
    const float* __restrict__ W_out, const float* __restrict__ b_out,
    float* __restrict__ out)
{
    __shared__ float wt_s[WTN];                 // 65 KB
    __shared__ int   syms[Tlen];                // 4 KB
    __shared__ __align__(16) float hbuf[2][HBUFN];
    __shared__ int   len_sh;

    const int tid = threadIdx.x;
    const int b   = blockIdx.x;
    const int wv  = tid >> 6;
    const int l   = tid & 63;
    const int G   = (wv << 3) + (l >> 3);   // group 0..31, owns outputs 4G..4G+3
    const int j   = l & 7;                  // K-chunk index within group
    const int eo  = 4 * G + (j & 3);        // element this lane writes (j<4)

    if (tid == 0) len_sh = Tlen;
    for (int k = tid; k < 2 * HBUFN; k += NTHR) ((float*)hbuf)[k] = 0.0f;

    // W_hh rows 4G..4G+3, cols [16j,16j+16) -> 64 registers
    float w[64];
    #pragma unroll
    for (int r = 0; r < 4; r++) {
        const float4* wrow = (const float4*)(W_hh + (4 * G + r) * Hdim + 16 * j);
        #pragma unroll
        for (int k4 = 0; k4 < 4; k4++) {
            float4 t4 = wrow[k4];
            w[r * 16 + 4 * k4 + 0] = t4.x; w[r * 16 + 4 * k4 + 1] = t4.y;
            w[r * 16 + 4 * k4 + 2] = t4.z; w[r * 16 + 4 * k4 + 3] = t4.w;
        }
    }
    const float bias = b_ih[eo] + b_hh[eo];

    // stage wt -> LDS, coalesced float4
    {
        const float4* src = (const float4*)wt;
        float4* dst = (float4*)wt_s;
        for (int k = tid; k < WTN / 4; k += NTHR) dst[k] = src[k];
    }

    // Decode this block's one-hot rows (512 KB contiguous, float4 coalesced).
    const float4* xb = (const float4*)(x + (size_t)b * Tlen * Vocab);
    for (int k = tid; k < (Tlen * Vocab) / 4; k += NTHR) {
        float4 v = xb[k];
        int c = -1;
        if      (v.x > 0.5f) c = 0;
        else if (v.y > 0.5f) c = 1;
        else if (v.z > 0.5f) c = 2;
        else if (v.w > 0.5f) c = 3;
        if (c >= 0) syms[k >> 5] = ((k & 31) << 2) + c;  // 32 float4 per row
    }
    __syncthreads();

    // length = first t with sym==0 (pad), else Tlen
    {
        int lm = Tlen;
        for (int k = tid; k < Tlen; k += NTHR)
            if (syms[k] == 0 && k < lm) lm = k;
        if (lm < Tlen) atomicMin(&len_sh, lm);
    }
    __syncthreads();
    const int len = len_sh;

    // pre pipeline: value for t ready (pre_v), t+1 in flight (p_t1),
    // symbol for t+2 in register (s_t2).
    float pre_v = 0.0f, p_t1 = 0.0f;
    int   s_t2 = 1;
    if (len > 0) pre_v = wt_s[(syms[0] - 1) * Hdim + eo];
    if (len > 1) p_t1  = wt_s[(syms[1] - 1) * Hdim + eo];
    if (len > 2) s_t2  = syms[2];

    const float4* rd0 = (const float4*)(hbuf[0] + j * HSTR);
    const float4* rd1 = (const float4*)(hbuf[1] + j * HSTR);
    const int waddr = HADDR(eo);

    for (int t = 0; t < len; t++) {
        // Pin W in VGPRs every iteration (opaque redefinition).
        #pragma unroll
        for (int k = 0; k < 64; k += 8)
            asm volatile("" : "+v"(w[k]), "+v"(w[k+1]), "+v"(w[k+2]), "+v"(w[k+3]),
                             "+v"(w[k+4]), "+v"(w[k+5]), "+v"(w[k+6]), "+v"(w[k+7]));

        float p_t2 = wt_s[(s_t2 - 1) * Hdim + eo];   // LDS gather for t+2
        int   s_t3 = (t + 3 < len) ? syms[t + 3] : 1;

        const float4* hsrc = (t & 1) ? rd1 : rd0;
        float4 h0 = hsrc[0], h1 = hsrc[1], h2 = hsrc[2], h3 = hsrc[3];
        float hv[16] = {h0.x,h0.y,h0.z,h0.w, h1.x,h1.y,h1.z,h1.w,
                        h2.x,h2.y,h2.z,h2.w, h3.x,h3.y,h3.z,h3.w};

        float s[4];
        #pragma unroll
        for (int r = 0; r < 4; r++) {
            float a0 = 0.0f, a1 = 0.0f;
            #pragma unroll
            for (int k = 0; k < 8; k++) {
                a0 = fmaf(w[r * 16 + k],     hv[k],     a0);
                a1 = fmaf(w[r * 16 + 8 + k], hv[8 + k], a1);
            }
            s[r] = a0 + a1;
        }
        // reduce over the 8-lane K-group
        #pragma unroll
        for (int r = 0; r < 4; r++) {
            s[r] += dpp_xor1(s[r]);
            s[r] += dpp_xor2(s[r]);
            s[r] += __shfl_xor(s[r], 4, 64);
        }
        int rs = j & 3;
        float s_own = (rs == 0) ? s[0] : (rs == 1) ? s[1] : (rs == 2) ? s[2] : s[3];
        float hn = tanh_fast(s_own + pre_v + bias);
        if (j < 4) hbuf[(t + 1) & 1][waddr] = hn;
        pre_v = p_t1; p_t1 = p_t2; s_t2 = s_t3;
        __syncthreads();
    }

    // epilogue: hidden state + softmax head
    const float* hf = hbuf[len & 1];
    if (tid < Hdim)
        out[2 * Bsz + b * Hdim + tid] = hf[HADDR(tid)];
    if (tid < 64) {
        float h0 = hf[HADDR(tid)];
        float h1 = hf[HADDR(tid + 64)];
        float p0 = W_out[tid] * h0 + W_out[64 + tid] * h1;
        float p1 = W_out[128 + tid] * h0 + W_out[192 + tid] * h1;
        #pragma unroll
        for (int off = 32; off > 0; off >>= 1) {
            p0 += __shfl_down(p0, off, 64);
            p1 += __shfl_down(p1, off, 64);
        }
        if (tid == 0) {
            float l0 = p0 + b_out[0], l1 = p1 + b_out[1];
            float m  = fmaxf(l0, l1);
            float e0 = __expf(l0 - m), e1 = __expf(l1 - m);
            float d  = e0 + e1;
            out[b * 2 + 0] = e0 / d;
            out[b * 2 + 1] = e1 / d;
        }
    }
}

extern "C" void kernel_launch(void* const* d_in, const int* in_sizes, int n_in,
                              void* d_out, int out_size, void* d_ws, size_t ws_size,
                              hipStream_t stream) {
    const float* x     = (const float*)d_in[0];
    const float* W_ih  = (const float*)d_in[1];
    const float* W_hh  = (const float*)d_in[2];
    const float* b_ih  = (const float*)d_in[3];
    const float* b_hh  = (const float*)d_in[4];
    const float* W_out = (const float*)d_in[5];
    const float* b_out = (const float*)d_in[6];
    float* out = (float*)d_out;

    float* wt = (float*)d_ws;  // (V-1) x H floats = 65 KB

    const int NTRN = (WTN + 255) / 256;  // 64 blocks
    transpose_kernel<<<NTRN, 256, 0, stream>>>(W_ih, wt);
    rnn_kernel<<<Bsz, NTHR, 0, stream>>>(x, wt, W_hh, b_ih, b_hh, W_out, b_out, out);
}

// Round 6
// 527.631 us; speedup vs baseline: 1.3050x; 1.3050x over previous
//
#include <hip/hip_runtime.h>
#include <stdint.h>

#define Bsz   256
#define Tlen  1024
#define Vocab 128
#define Hdim  128
#define NTHR  512
#define WTN   ((Vocab - 1) * Hdim)   // 127*128 = 16256 floats

typedef _Float16 half2_t __attribute__((ext_vector_type(2)));

// h stored in LDS as f16: 8 chunks of 16 halves (32 B data) at 48-B stride.
// Chunk bases -> banks {0,12,24,4,16,28,8,20}; +16B -> {4,16,28,8,20,0,12,24}:
// both b128 read phases conflict-free across the 8 distinct j addresses.
#define HCHB  48                    // chunk stride in bytes
#define HBUFI (8 * HCHB / 4)        // ints per buffer = 96

__device__ __forceinline__ float tanh_fast(float x) {
    // tanh(x) = 1 - 2/(exp2(2x*log2e)+1); exact limits at +-inf
    float e = __builtin_amdgcn_exp2f(x * 2.885390081777927f);
    return 1.0f - 2.0f * __builtin_amdgcn_rcpf(e + 1.0f);
}

// DPP reduction helpers (pure VALU, no LDS pipe)
__device__ __forceinline__ float dpp_xor1(float s) {
    return __int_as_float(__builtin_amdgcn_mov_dpp(__float_as_int(s), 0xB1, 0xF, 0xF, true));  // quad_perm(1,0,3,2)
}
__device__ __forceinline__ float dpp_xor2(float s) {
    return __int_as_float(__builtin_amdgcn_mov_dpp(__float_as_int(s), 0x4E, 0xF, 0xF, true));  // quad_perm(2,3,0,1)
}
__device__ __forceinline__ float dpp_hm(float s) {
    // row_half_mirror: lane j -> 7-j within each 8-lane half-row. After
    // xor1+xor2 the value is quad-invariant, so this equals xor4.
    return __int_as_float(__builtin_amdgcn_mov_dpp(__float_as_int(s), 0x141, 0xF, 0xF, true));
}

// Tiny prep: transpose W_ih (H x V-1) -> wt (V-1 x H).
__global__ __launch_bounds__(256) void transpose_kernel(
    const float* __restrict__ W_ih, float* __restrict__ wt)
{
    int idx = blockIdx.x * 256 + threadIdx.x;
    if (idx < WTN) {
        int h = idx / (Vocab - 1);
        int f = idx - h * (Vocab - 1);
        wt[f * Hdim + h] = W_ih[idx];   // wt[f][h] = W_ih[h][f]
    }
}

// One block (512 thr, 8 waves = 2/SIMD) per sequence. 8-lane group g=tid>>3
// owns outputs {2g, 2g+1}; lane j=tid&7 covers k in [16j,16j+16) as f16
// pairs with v_dot2_f32_f16 (fp32 accumulate). W_hh pinned in VGPRs as 16
// packed f16x2. Reduction = 3 DPP adds (xor1, xor2, half_mirror) - zero
// LDS swizzles. One barrier per step, zero global ops in loop.
__global__ __launch_bounds__(NTHR, 2) void rnn_kernel(
    const float* __restrict__ x, const float* __restrict__ wt,
    const float* __restrict__ W_hh,
    const float* __restrict__ b_ih, const float* __restrict__ b_hh,
    const float* __restrict__ W_out, const float* __restrict__ b_out,
    float* __restrict__ out)
{
    __shared__ float wt_s[WTN];                    // 65 KB (pre gather table)
    __shared__ int   syms[Tlen];                   // 4 KB
    __shared__ __align__(16) int hbuf[2][HBUFI];   // f16 h, double-buffered
    __shared__ int   len_sh;

    const int tid = threadIdx.x;
    const int b   = blockIdx.x;
    const int g   = tid >> 3;   // group 0..63, owns outputs 2g, 2g+1
    const int j   = tid & 7;    // K-chunk index within group

    if (tid == 0) len_sh = Tlen;
    for (int k = tid; k < 2 * HBUFI; k += NTHR) ((int*)hbuf)[k] = 0;  // h0 = 0

    // W_hh rows 2g,2g+1, cols [16j,16j+16) -> 16 packed f16x2 registers
    int wp[16];
    #pragma unroll
    for (int r = 0; r < 2; r++) {
        const float4* wrow = (const float4*)(W_hh + (2 * g + r) * Hdim + 16 * j);
        #pragma unroll
        for (int q4 = 0; q4 < 4; q4++) {
            float4 t4 = wrow[q4];
            wp[r * 8 + q4 * 2 + 0] = __builtin_bit_cast(int, __builtin_amdgcn_cvt_pkrtz(t4.x, t4.y));
            wp[r * 8 + q4 * 2 + 1] = __builtin_bit_cast(int, __builtin_amdgcn_cvt_pkrtz(t4.z, t4.w));
        }
    }
    const float bias0 = b_ih[2 * g]     + b_hh[2 * g];
    const float bias1 = b_ih[2 * g + 1] + b_hh[2 * g + 1];

    // stage wt -> LDS, coalesced float4
    {
        const float4* src = (const float4*)wt;
        float4* dst = (float4*)wt_s;
        for (int k = tid; k < WTN / 4; k += NTHR) dst[k] = src[k];
    }

    // Decode this block's one-hot rows (512 KB contiguous, float4 coalesced).
    const float4* xb = (const float4*)(x + (size_t)b * Tlen * Vocab);
    for (int k = tid; k < (Tlen * Vocab) / 4; k += NTHR) {
        float4 v = xb[k];
        int c = -1;
        if      (v.x > 0.5f) c = 0;
        else if (v.y > 0.5f) c = 1;
        else if (v.z > 0.5f) c = 2;
        else if (v.w > 0.5f) c = 3;
        if (c >= 0) syms[k >> 5] = ((k & 31) << 2) + c;  // 32 float4 per row
    }
    __syncthreads();

    // length = first t with sym==0 (pad), else Tlen
    {
        int lm = Tlen;
        for (int k = tid; k < Tlen; k += NTHR)
            if (syms[k] == 0 && k < lm) lm = k;
        if (lm < Tlen) atomicMin(&len_sh, lm);
    }
    __syncthreads();
    const int len = len_sh;

    // pre pipeline: float2 (elements 2g,2g+1) for t ready, t+1 in flight,
    // symbol for t+2 in register.
    const float2* wt2 = (const float2*)wt_s;   // pair index: (sym-1)*64 + g
    float2 pre_v = {0.0f, 0.0f}, p_t1 = {0.0f, 0.0f};
    int s_t2 = 1;
    if (len > 0) pre_v = wt2[(syms[0] - 1) * 64 + g];
    if (len > 1) p_t1  = wt2[(syms[1] - 1) * 64 + g];
    if (len > 2) s_t2  = syms[2];

    const char* hb0 = (const char*)hbuf[0];
    const char* hb1 = (const char*)hbuf[1];
    const int roff = j * HCHB;
    const int woff = (g >> 3) * HCHB + ((2 * g) & 15) * 2;

    for (int t = 0; t < len; t++) {
        // Pin packed W in VGPRs every iteration (opaque redefinition).
        #pragma unroll
        for (int k = 0; k < 16; k += 8)
            asm volatile("" : "+v"(wp[k]), "+v"(wp[k+1]), "+v"(wp[k+2]), "+v"(wp[k+3]),
                             "+v"(wp[k+4]), "+v"(wp[k+5]), "+v"(wp[k+6]), "+v"(wp[k+7]));

        float2 p_t2 = wt2[(s_t2 - 1) * 64 + g];   // LDS b64 gather for t+2
        int   s_t3 = (t + 3 < len) ? syms[t + 3] : 1;

        const char* hb = (t & 1) ? hb1 : hb0;
        uint4 r0 = *(const uint4*)(hb + roff);
        uint4 r1 = *(const uint4*)(hb + roff + 16);
        unsigned hr[8] = {r0.x, r0.y, r0.z, r0.w, r1.x, r1.y, r1.z, r1.w};

        float a0 = 0.0f, a1 = 0.0f;
        #pragma unroll
        for (int p = 0; p < 8; p++) {
            half2_t hh = __builtin_bit_cast(half2_t, hr[p]);
            a0 = __builtin_amdgcn_fdot2(hh, __builtin_bit_cast(half2_t, wp[p]),     a0, false);
            a1 = __builtin_amdgcn_fdot2(hh, __builtin_bit_cast(half2_t, wp[8 + p]), a1, false);
        }
        a0 += dpp_xor1(a0); a1 += dpp_xor1(a1);
        a0 += dpp_xor2(a0); a1 += dpp_xor2(a1);
        a0 += dpp_hm(a0);   a1 += dpp_hm(a1);

        if (j == 0) {
            float h0 = tanh_fast(a0 + pre_v.x + bias0);
            float h1 = tanh_fast(a1 + pre_v.y + bias1);
            int pk = __builtin_bit_cast(int, __builtin_amdgcn_cvt_pkrtz(h0, h1));
            *(int*)(((char*)hbuf[(t + 1) & 1]) + woff) = pk;
        }
        pre_v = p_t1; p_t1 = p_t2; s_t2 = s_t3;
        __syncthreads();
    }

    // epilogue: hidden state + softmax head
    const _Float16* hf = (const _Float16*)hbuf[len & 1];
    #define HGET(e) ((float)hf[((e) >> 4) * 24 + ((e) & 15)])
    if (tid < Hdim)
        out[2 * Bsz + b * Hdim + tid] = HGET(tid);
    if (tid < 64) {
        float h0 = HGET(tid);
        float h1 = HGET(tid + 64);
        float p0 = W_out[tid] * h0 + W_out[64 + tid] * h1;
        float p1 = W_out[128 + tid] * h0 + W_out[192 + tid] * h1;
        #pragma unroll
        for (int off = 32; off > 0; off >>= 1) {
            p0 += __shfl_down(p0, off, 64);
            p1 += __shfl_down(p1, off, 64);
        }
        if (tid == 0) {
            float l0 = p0 + b_out[0], l1 = p1 + b_out[1];
            float m  = fmaxf(l0, l1);
            float e0 = __expf(l0 - m), e1 = __expf(l1 - m);
            float d  = e0 + e1;
            out[b * 2 + 0] = e0 / d;
            out[b * 2 + 1] = e1 / d;
        }
    }
    #undef HGET
}

extern "C" void kernel_launch(void* const* d_in, const int* in_sizes, int n_in,
                              void* d_out, int out_size, void* d_ws, size_t ws_size,
                              hipStream_t stream) {
    const float* x     = (const float*)d_in[0];
    const float* W_ih  = (const float*)d_in[1];
    const float* W_hh  = (const float*)d_in[2];
    const float* b_ih  = (const float*)d_in[3];
    const float* b_hh  = (const float*)d_in[4];
    const float* W_out = (const float*)d_in[5];
    const float* b_out = (const float*)d_in[6];
    float* out = (float*)d_out;

    float* wt = (float*)d_ws;  // (V-1) x H floats = 65 KB

    const int NTRN = (WTN + 255) / 256;  // 64 blocks
    transpose_kernel<<<NTRN, 256, 0, stream>>>(W_ih, wt);
    rnn_kernel<<<Bsz, NTHR, 0, stream>>>(x, wt, W_hh, b_ih, b_hh, W_out, b_out, out);
}